// Round 10
// baseline (287.825 us; speedup 1.0000x reference)
//
#include <hip/hip_runtime.h>
#include <hip/hip_bf16.h>
#include <cstddef>

#define RES 256
#define NCH 32
#define NPT 131072   // points per batch
#define NB  4

typedef _Float16 half8 __attribute__((ext_vector_type(8)));
typedef _Float16 half4 __attribute__((ext_vector_type(4)));
typedef float    f32x4 __attribute__((ext_vector_type(4)));

#define FEAT_STRIDE 40    // halves per feat row (32+8 pad, 80B rows, 16B-aligned)
#define H0_STRIDE   136   // halves per h0 row (128+8 pad, 272B rows, 16B-aligned)
#define WAVE_LDS    (32 * H0_STRIDE)   // halves per wave (8704 B)

// ---------------------------------------------------------------------------
// Transpose + fp16 convert + weight prep, one kernel.
// bp 0..11: [bp][c][y][x] f32 -> [bp][y][x][c] f16 (1 row/block).
// bp == 12: convert w0/w1 to fp16 with scaling (w0h = w0*16, w1h = w1).
// (feat scaled x256 at sampling; net h0 scale 4096, undone via w2/4096.)
// ---------------------------------------------------------------------------
__global__ __launch_bounds__(256) void transpose_prep_kernel(
    const float* __restrict__ in,
    const float* __restrict__ w0, const float* __restrict__ w1,
    _Float16* __restrict__ out,
    _Float16* __restrict__ w0h, _Float16* __restrict__ w1h)
{
    const int bp = blockIdx.y;                 // 0..12
    const int t  = threadIdx.x;

    if (bp == 12) {                            // weight-prep blocks
        const int i = blockIdx.x * 256 + t;
        if (i < 128 * NCH)  w0h[i] = (_Float16)(w0[i] * 16.0f);
        if (i < 128 * 128)  w1h[i] = (_Float16)w1[i];
        return;
    }

    __shared__ _Float16 tileh[NCH][RES + 8];   // 16.5 KB
    const int y = blockIdx.x;                  // 0..255

    const float4* src4 = (const float4*)(in + (size_t)bp * NCH * RES * RES);
    const int lane64 = t & 63;
    const int cq     = t >> 6;                 // 0..3
    #pragma unroll
    for (int i = 0; i < 8; ++i) {
        const int c = cq * 8 + i;
        const float4 v = src4[(size_t)c * (RES * RES / 4) + y * (RES / 4) + lane64];
        half4 h = { (_Float16)v.x, (_Float16)v.y, (_Float16)v.z, (_Float16)v.w };
        *(half4*)&tileh[c][lane64 * 4] = h;
    }
    __syncthreads();

    _Float16* dst = out + ((size_t)bp * RES * RES + (size_t)y * RES) * NCH;
    const int x = t;                           // texel 0..255
    #pragma unroll
    for (int cg = 0; cg < 4; ++cg) {
        half8 h;
        #pragma unroll
        for (int k = 0; k < 8; ++k)
            h[k] = tileh[cg * 8 + k][x];
        *(half8*)&dst[(size_t)x * NCH + cg * 8] = h;
    }
}

// ---------------------------------------------------------------------------
// Fused sample + MFMA MLP, one wave per block, zero barriers.
// R10: phase A issues ALL 24 corner loads in one batch (flat L0/L1 arrays,
// ~96 dest VGPRs in flight) before any interpolation -- R9 showed the
// gather was concurrency-limited (VGPR 68 -> only ~8 loads in flight,
// 3.2 TB/s vs the 4.3 TB/s standalone-sampler rate). launch_bounds(64,1):
// VGPR cap 256 so the load batch cannot spill (R5: spill = catastrophe);
// at ~140 VGPR occupancy is ~12 waves/CU >= the measured ~10.
// MFMA 16x16x32 f16 layouts (verified m89/m120 + rounds 3/4/6/7):
//   A: lane holds A[m=lane&15][k=quad*8+j]
//   B: lane holds B[k=quad*8+j][n=lane&15] = W[n][k] row-major 8-contig
//   C/D: col n = lane&15, row m = quad*4+reg
// ---------------------------------------------------------------------------
__global__ __launch_bounds__(64, 1) void fused_kernel(
    const _Float16* __restrict__ planesT,   // [12][256][256][32] f16
    const float* __restrict__ coords,
    const _Float16* __restrict__ w0h,       // [128][32]  (x16)
    const _Float16* __restrict__ w1h,       // [128][128]
    const float* __restrict__ b0, const float* __restrict__ b1,
    const float* __restrict__ w2, const float* __restrict__ b2,
    float* __restrict__ out)
{
    __shared__ __align__(16) _Float16 wbase[WAVE_LDS];   // 8.7 KB, wave-private

    const int tid  = threadIdx.x;           // 0..63 (one wave)
    const int l15  = tid & 15;
    const int quad = tid >> 4;

    // ================= phase A: bilinear sample, 2 threads/point ===========
    {
        const int p  = tid >> 1;                    // wave-local point 0..31
        const int hf = tid & 1;                     // channel half
        const int gp = blockIdx.x * 32 + p;
        const int b  = gp >> 17;                    // NPT = 2^17
        const float cx = coords[(size_t)gp * 3 + 0];
        const float cy = coords[(size_t)gp * 3 + 1];
        const float cz = coords[(size_t)gp * 3 + 2];

        // ---- step 1: all 12 corner offsets + weights
        int   offs[12];
        float wgt[12];
        #pragma unroll
        for (int pl = 0; pl < 3; ++pl) {
            const float u = (pl == 0) ? cx : (pl == 1) ? cy : cx;
            const float v = (pl == 0) ? cy : cz;

            const float fx = (u + 1.0f) * 0.5f * (RES - 1);
            const float fy = (v + 1.0f) * 0.5f * (RES - 1);
            const float x0f = floorf(fx), y0f = floorf(fy);
            const float wx = fx - x0f, wy = fy - y0f;
            const int x0 = (int)x0f, y0 = (int)y0f;
            const bool vx1 = (x0 + 1) < RES;
            const bool vy1 = (y0 + 1) < RES;
            const int x1 = vx1 ? x0 + 1 : RES - 1;
            const int y1 = vy1 ? y0 + 1 : RES - 1;

            float w00 = (1.0f - wx) * (1.0f - wy);
            float w01 = wx * (1.0f - wy);
            float w10 = (1.0f - wx) * wy;
            float w11 = wx * wy;
            if (!vx1) { w01 = 0.0f; w11 = 0.0f; }
            if (!vy1) { w10 = 0.0f; w11 = 0.0f; }

            // offset (halves) = ((b*3+pl)*65536 + y*256 + x)*32 + hf*16
            const int pbase = ((b * 3 + pl) << 21) + (hf << 4);
            offs[pl * 4 + 0] = pbase + (y0 << 13) + (x0 << 5);
            offs[pl * 4 + 1] = pbase + (y0 << 13) + (x1 << 5);
            offs[pl * 4 + 2] = pbase + (y1 << 13) + (x0 << 5);
            offs[pl * 4 + 3] = pbase + (y1 << 13) + (x1 << 5);
            wgt[pl * 4 + 0] = w00; wgt[pl * 4 + 1] = w01;
            wgt[pl * 4 + 2] = w10; wgt[pl * 4 + 3] = w11;
        }

        // ---- step 2: issue ALL 24 loads (96 dest VGPRs; cap 256 -> no spill)
        half8 L0[12], L1[12];
        #pragma unroll
        for (int i = 0; i < 12; ++i) {
            const _Float16* cp = planesT + (size_t)(unsigned)offs[i];
            L0[i] = *(const half8*)cp;
            L1[i] = *(const half8*)(cp + 8);
        }

        // ---- step 3: interpolate (identical FMA order to R6-R9: bit-exact)
        float prod[16];
        #pragma unroll
        for (int pl = 0; pl < 3; ++pl) {
            #pragma unroll
            for (int k = 0; k < 8; ++k) {
                const float t0 =
                    fmaf((float)L0[pl*4+3][k], wgt[pl*4+3],
                    fmaf((float)L0[pl*4+2][k], wgt[pl*4+2],
                    fmaf((float)L0[pl*4+1][k], wgt[pl*4+1],
                         (float)L0[pl*4+0][k] * wgt[pl*4+0])));
                const float t1 =
                    fmaf((float)L1[pl*4+3][k], wgt[pl*4+3],
                    fmaf((float)L1[pl*4+2][k], wgt[pl*4+2],
                    fmaf((float)L1[pl*4+1][k], wgt[pl*4+1],
                         (float)L1[pl*4+0][k] * wgt[pl*4+0])));
                if (pl == 0) { prod[k] = t0;  prod[8 + k] = t1; }
                else         { prod[k] *= t0; prod[8 + k] *= t1; }
            }
        }

        half8 o0, o1;
        #pragma unroll
        for (int k = 0; k < 8; ++k) {
            o0[k] = (_Float16)(prod[k]     * 256.0f);
            o1[k] = (_Float16)(prod[8 + k] * 256.0f);
        }
        *(half8*)&wbase[p * FEAT_STRIDE + hf * 16 + 0] = o0;
        *(half8*)&wbase[p * FEAT_STRIDE + hf * 16 + 8] = o1;
    }

    // a0 reads: same wave wrote these rows; lgkmcnt orders write->read.
    half8 a0[2];
    #pragma unroll
    for (int mt = 0; mt < 2; ++mt)
        a0[mt] = *(const half8*)&wbase[(mt * 16 + l15) * FEAT_STRIDE + quad * 8];

    // per-lane bias/weight scalars
    float b0v[8], b1v[8], w2s[8];
    #pragma unroll
    for (int nt = 0; nt < 8; ++nt) {
        b0v[nt] = b0[nt * 16 + l15] * 4096.0f;
        b1v[nt] = b1[nt * 16 + l15] * 4096.0f;
        w2s[nt] = w2[nt * 16 + l15] * (1.0f / 4096.0f);
    }

    // ================= layer 0 (h0 writes clobber feat region; WAR ordered
    // by lgkmcnt since a0 loads precede in program order) ===================
    #pragma unroll 1
    for (int nt = 0; nt < 8; ++nt) {
        const half8 bfr = *(const half8*)&w0h[(nt * 16 + l15) * NCH + quad * 8];
        f32x4 acc[2];
        #pragma unroll
        for (int mt = 0; mt < 2; ++mt) {
            acc[mt] = (f32x4){0.f, 0.f, 0.f, 0.f};
            acc[mt] = __builtin_amdgcn_mfma_f32_16x16x32_f16(
                a0[mt], bfr, acc[mt], 0, 0, 0);
        }
        #pragma unroll
        for (int mt = 0; mt < 2; ++mt)
            #pragma unroll
            for (int r = 0; r < 4; ++r) {
                const float hval = fmaxf(acc[mt][r] + b0v[nt], 0.0f);
                wbase[(mt * 16 + quad * 4 + r) * H0_STRIDE + nt * 16 + l15]
                    = (_Float16)hval;
            }
    }

    // ================= layer 1 (+ fused layer-2 epilogue) ==================
    half8 a1[2][4];
    #pragma unroll
    for (int mt = 0; mt < 2; ++mt)
        #pragma unroll
        for (int ks = 0; ks < 4; ++ks)
            a1[mt][ks] = *(const half8*)
                &wbase[(mt * 16 + l15) * H0_STRIDE + ks * 32 + quad * 8];

    float part[2][4];
    #pragma unroll
    for (int mt = 0; mt < 2; ++mt)
        #pragma unroll
        for (int r = 0; r < 4; ++r) part[mt][r] = 0.0f;

    #pragma unroll 2
    for (int nt = 0; nt < 8; ++nt) {
        f32x4 acc[2];
        #pragma unroll
        for (int mt = 0; mt < 2; ++mt) acc[mt] = (f32x4){0.f, 0.f, 0.f, 0.f};
        #pragma unroll
        for (int ks = 0; ks < 4; ++ks) {
            const half8 bfr = *(const half8*)
                &w1h[(nt * 16 + l15) * 128 + ks * 32 + quad * 8];
            #pragma unroll
            for (int mt = 0; mt < 2; ++mt)
                acc[mt] = __builtin_amdgcn_mfma_f32_16x16x32_f16(
                    a1[mt][ks], bfr, acc[mt], 0, 0, 0);
        }
        #pragma unroll
        for (int mt = 0; mt < 2; ++mt)
            #pragma unroll
            for (int r = 0; r < 4; ++r)
                part[mt][r] = fmaf(w2s[nt], fmaxf(acc[mt][r] + b1v[nt], 0.0f),
                                   part[mt][r]);
    }

    // reduce across the 16 lanes (l15) of each quad-group
    #pragma unroll
    for (int mt = 0; mt < 2; ++mt)
        #pragma unroll
        for (int r = 0; r < 4; ++r) {
            float s = part[mt][r];
            s += __shfl_xor(s, 1);
            s += __shfl_xor(s, 2);
            s += __shfl_xor(s, 4);
            s += __shfl_xor(s, 8);
            part[mt][r] = s;
        }

    if (l15 == 0) {
        const float bias2 = b2[0];
        const int base = blockIdx.x * 32;
        #pragma unroll
        for (int mt = 0; mt < 2; ++mt)
            #pragma unroll
            for (int r = 0; r < 4; ++r)
                out[base + mt * 16 + quad * 4 + r] = part[mt][r] + bias2;
    }
}

// ---------------------------------------------------------------------------
// Fallback (ws too small): round-1 fused fp32 kernel on original layout.
// ---------------------------------------------------------------------------
__global__ __launch_bounds__(256) void fused_fallback(
    const float* __restrict__ planes, const float* __restrict__ coords,
    const float* __restrict__ w0, const float* __restrict__ b0,
    const float* __restrict__ w1, const float* __restrict__ b1,
    const float* __restrict__ w2, const float* __restrict__ b2,
    float* __restrict__ out)
{
    const int t = blockIdx.x * 256 + threadIdx.x;
    const int b = t >> 17;
    const float cx = coords[(size_t)t * 3 + 0];
    const float cy = coords[(size_t)t * 3 + 1];
    const float cz = coords[(size_t)t * 3 + 2];
    float feat[NCH];
    #pragma unroll
    for (int p = 0; p < 3; ++p) {
        const float u = (p == 0) ? cx : (p == 1) ? cy : cx;
        const float v = (p == 0) ? cy : cz;
        const float fx = (u + 1.0f) * 0.5f * (RES - 1);
        const float fy = (v + 1.0f) * 0.5f * (RES - 1);
        const float x0f = floorf(fx), y0f = floorf(fy);
        const float wx = fx - x0f, wy = fy - y0f;
        const int x0 = (int)x0f, y0 = (int)y0f;
        const bool vx1 = (x0 + 1) < RES, vy1 = (y0 + 1) < RES;
        const int x1 = vx1 ? x0 + 1 : RES - 1;
        const int y1 = vy1 ? y0 + 1 : RES - 1;
        float w00 = (1.0f - wx) * (1.0f - wy), w01 = wx * (1.0f - wy);
        float w10 = (1.0f - wx) * wy, w11 = wx * wy;
        if (!vx1) { w01 = 0.0f; w11 = 0.0f; }
        if (!vy1) { w10 = 0.0f; w11 = 0.0f; }
        const float* base = planes + (size_t)(b * 3 + p) * NCH * RES * RES;
        const float* p00 = base + (size_t)y0 * RES + x0;
        const float* p01 = base + (size_t)y0 * RES + x1;
        const float* p10 = base + (size_t)y1 * RES + x0;
        const float* p11 = base + (size_t)y1 * RES + x1;
        #pragma unroll
        for (int c = 0; c < NCH; ++c) {
            const size_t off = (size_t)c * RES * RES;
            float s = p00[off] * w00;
            s = fmaf(p01[off], w01, s);
            s = fmaf(p10[off], w10, s);
            s = fmaf(p11[off], w11, s);
            if (p == 0) feat[c] = s; else feat[c] *= s;
        }
    }
    float h0[128];
    #pragma unroll
    for (int g = 0; g < 128; ++g) {
        const float* wr = w0 + g * NCH;
        float aA = b0[g], aB = 0.0f;
        #pragma unroll
        for (int c = 0; c < NCH; c += 2) {
            aA = fmaf(wr[c], feat[c], aA);
            aB = fmaf(wr[c + 1], feat[c + 1], aB);
        }
        h0[g] = fmaxf(aA + aB, 0.0f);
    }
    float o = b2[0];
    for (int g = 0; g < 128; ++g) {
        const float* wr = w1 + g * 128;
        float aA = b1[g], aB = 0.0f, aC = 0.0f, aD = 0.0f;
        #pragma unroll
        for (int h = 0; h < 128; h += 4) {
            aA = fmaf(wr[h], h0[h], aA);
            aB = fmaf(wr[h + 1], h0[h + 1], aB);
            aC = fmaf(wr[h + 2], h0[h + 2], aC);
            aD = fmaf(wr[h + 3], h0[h + 3], aD);
        }
        o = fmaf(fmaxf((aA + aB) + (aC + aD), 0.0f), w2[g], o);
    }
    out[t] = o;
}

// ---------------------------------------------------------------------------
extern "C" void kernel_launch(void* const* d_in, const int* in_sizes, int n_in,
                              void* d_out, int out_size, void* d_ws, size_t ws_size,
                              hipStream_t stream)
{
    const float* trip   = (const float*)d_in[0];
    const float* coords = (const float*)d_in[1];
    const float* w0     = (const float*)d_in[2];
    const float* b0     = (const float*)d_in[3];
    const float* w1     = (const float*)d_in[4];
    const float* b1     = (const float*)d_in[5];
    const float* w2     = (const float*)d_in[6];
    const float* b2     = (const float*)d_in[7];
    float* out = (float*)d_out;

    const size_t planesTBytes = (size_t)NB * 3 * RES * RES * NCH * 2;   // 50331648
    const size_t w0hBytes = 128 * NCH * 2;                              // 8192
    const size_t w1hBytes = 128 * 128 * 2;                              // 32768
    const size_t needed = planesTBytes + w0hBytes + w1hBytes;

    if (ws_size >= needed) {
        _Float16* planesT = (_Float16*)d_ws;
        _Float16* w0h     = (_Float16*)((char*)d_ws + planesTBytes);
        _Float16* w1h     = (_Float16*)((char*)d_ws + planesTBytes + w0hBytes);

        transpose_prep_kernel<<<dim3(RES, NB * 3 + 1), 256, 0, stream>>>(
            trip, w0, w1, planesT, w0h, w1h);
        fused_kernel<<<(NB * NPT) / 32, 64, 0, stream>>>(
            planesT, coords, w0h, w1h, b0, b1, w2, b2, out);
    } else {
        fused_fallback<<<(NB * NPT) / 256, 256, 0, stream>>>(
            trip, coords, w0, b0, w1, b1, w2, b2, out);
    }
}

// Round 11
// 275.301 us; speedup vs baseline: 1.0455x; 1.0455x over previous
//
#include <hip/hip_runtime.h>
#include <hip/hip_bf16.h>
#include <cstddef>

#define RES 256
#define NCH 32
#define NPT 131072   // points per batch
#define NB  4

typedef _Float16 half8 __attribute__((ext_vector_type(8)));
typedef _Float16 half4 __attribute__((ext_vector_type(4)));
typedef float    f32x4 __attribute__((ext_vector_type(4)));

#define FEAT_STRIDE 40    // halves per feat row (32+8 pad, 80B rows, 16B-aligned)
#define H0_STRIDE   136   // halves per h0 row (128+8 pad, 272B rows, 16B-aligned)
#define WAVE_LDS    (32 * H0_STRIDE)   // halves per wave (8704 B)

// ---------------------------------------------------------------------------
// Transpose + fp16 convert + weight prep, one kernel.
// bp 0..11: [bp][c][y][x] f32 -> [bp][y][x][c] f16 (1 row/block).
// bp == 12: convert w0/w1 to fp16 with scaling (w0h = w0*16, w1h = w1).
// (feat scaled x256 at sampling; net h0 scale 4096, undone via w2/4096.)
// ---------------------------------------------------------------------------
__global__ __launch_bounds__(256) void transpose_prep_kernel(
    const float* __restrict__ in,
    const float* __restrict__ w0, const float* __restrict__ w1,
    _Float16* __restrict__ out,
    _Float16* __restrict__ w0h, _Float16* __restrict__ w1h)
{
    const int bp = blockIdx.y;                 // 0..12
    const int t  = threadIdx.x;

    if (bp == 12) {                            // weight-prep blocks
        const int i = blockIdx.x * 256 + t;
        if (i < 128 * NCH)  w0h[i] = (_Float16)(w0[i] * 16.0f);
        if (i < 128 * 128)  w1h[i] = (_Float16)w1[i];
        return;
    }

    __shared__ _Float16 tileh[NCH][RES + 8];   // 16.5 KB
    const int y = blockIdx.x;                  // 0..255

    const float4* src4 = (const float4*)(in + (size_t)bp * NCH * RES * RES);
    const int lane64 = t & 63;
    const int cq     = t >> 6;                 // 0..3
    #pragma unroll
    for (int i = 0; i < 8; ++i) {
        const int c = cq * 8 + i;
        const float4 v = src4[(size_t)c * (RES * RES / 4) + y * (RES / 4) + lane64];
        half4 h = { (_Float16)v.x, (_Float16)v.y, (_Float16)v.z, (_Float16)v.w };
        *(half4*)&tileh[c][lane64 * 4] = h;
    }
    __syncthreads();

    _Float16* dst = out + ((size_t)bp * RES * RES + (size_t)y * RES) * NCH;
    const int x = t;                           // texel 0..255
    #pragma unroll
    for (int cg = 0; cg < 4; ++cg) {
        half8 h;
        #pragma unroll
        for (int k = 0; k < 8; ++k)
            h[k] = tileh[cg * 8 + k][x];
        *(half8*)&dst[(size_t)x * NCH + cg * 8] = h;
    }
}

// ---------------------------------------------------------------------------
// Fused sample + MFMA MLP, one wave per block, zero barriers.
// R11: the 24-corner-load batch is FENCED with sched_barrier(0) so the
// scheduler cannot sink loads to their uses (R10: compiler re-sank the
// batch, VGPR only 76, in-flight loads ~8, no speedup). Forcing all 24
// loads in flight triples per-wave outstanding sectors. ~200 live VGPRs
// peak < the 256 cap from launch_bounds(64,1) -> no spill.
// MFMA 16x16x32 f16 layouts (verified m89/m120 + rounds 3/4/6/7):
//   A: lane holds A[m=lane&15][k=quad*8+j]
//   B: lane holds B[k=quad*8+j][n=lane&15] = W[n][k] row-major 8-contig
//   C/D: col n = lane&15, row m = quad*4+reg
// ---------------------------------------------------------------------------
__global__ __launch_bounds__(64, 1) void fused_kernel(
    const _Float16* __restrict__ planesT,   // [12][256][256][32] f16
    const float* __restrict__ coords,
    const _Float16* __restrict__ w0h,       // [128][32]  (x16)
    const _Float16* __restrict__ w1h,       // [128][128]
    const float* __restrict__ b0, const float* __restrict__ b1,
    const float* __restrict__ w2, const float* __restrict__ b2,
    float* __restrict__ out)
{
    __shared__ __align__(16) _Float16 wbase[WAVE_LDS];   // 8.7 KB, wave-private

    const int tid  = threadIdx.x;           // 0..63 (one wave)
    const int l15  = tid & 15;
    const int quad = tid >> 4;

    // ================= phase A: bilinear sample, 2 threads/point ===========
    {
        const int p  = tid >> 1;                    // wave-local point 0..31
        const int hf = tid & 1;                     // channel half
        const int gp = blockIdx.x * 32 + p;
        const int b  = gp >> 17;                    // NPT = 2^17
        const float cx = coords[(size_t)gp * 3 + 0];
        const float cy = coords[(size_t)gp * 3 + 1];
        const float cz = coords[(size_t)gp * 3 + 2];

        // ---- step 1: all 12 corner offsets + weights
        int   offs[12];
        float wgt[12];
        #pragma unroll
        for (int pl = 0; pl < 3; ++pl) {
            const float u = (pl == 0) ? cx : (pl == 1) ? cy : cx;
            const float v = (pl == 0) ? cy : cz;

            const float fx = (u + 1.0f) * 0.5f * (RES - 1);
            const float fy = (v + 1.0f) * 0.5f * (RES - 1);
            const float x0f = floorf(fx), y0f = floorf(fy);
            const float wx = fx - x0f, wy = fy - y0f;
            const int x0 = (int)x0f, y0 = (int)y0f;
            const bool vx1 = (x0 + 1) < RES;
            const bool vy1 = (y0 + 1) < RES;
            const int x1 = vx1 ? x0 + 1 : RES - 1;
            const int y1 = vy1 ? y0 + 1 : RES - 1;

            float w00 = (1.0f - wx) * (1.0f - wy);
            float w01 = wx * (1.0f - wy);
            float w10 = (1.0f - wx) * wy;
            float w11 = wx * wy;
            if (!vx1) { w01 = 0.0f; w11 = 0.0f; }
            if (!vy1) { w10 = 0.0f; w11 = 0.0f; }

            // offset (halves) = ((b*3+pl)*65536 + y*256 + x)*32 + hf*16
            const int pbase = ((b * 3 + pl) << 21) + (hf << 4);
            offs[pl * 4 + 0] = pbase + (y0 << 13) + (x0 << 5);
            offs[pl * 4 + 1] = pbase + (y0 << 13) + (x1 << 5);
            offs[pl * 4 + 2] = pbase + (y1 << 13) + (x0 << 5);
            offs[pl * 4 + 3] = pbase + (y1 << 13) + (x1 << 5);
            wgt[pl * 4 + 0] = w00; wgt[pl * 4 + 1] = w01;
            wgt[pl * 4 + 2] = w10; wgt[pl * 4 + 3] = w11;
        }

        // ---- step 2: ALL 24 loads, fenced so the scheduler cannot sink them
        __builtin_amdgcn_sched_barrier(0);
        half8 L0[12], L1[12];
        #pragma unroll
        for (int i = 0; i < 12; ++i) {
            const _Float16* cp = planesT + (size_t)(unsigned)offs[i];
            L0[i] = *(const half8*)cp;
            L1[i] = *(const half8*)(cp + 8);
        }
        __builtin_amdgcn_sched_barrier(0);

        // ---- step 3: interpolate (identical FMA order to R6-R10: bit-exact)
        float prod[16];
        #pragma unroll
        for (int pl = 0; pl < 3; ++pl) {
            #pragma unroll
            for (int k = 0; k < 8; ++k) {
                const float t0 =
                    fmaf((float)L0[pl*4+3][k], wgt[pl*4+3],
                    fmaf((float)L0[pl*4+2][k], wgt[pl*4+2],
                    fmaf((float)L0[pl*4+1][k], wgt[pl*4+1],
                         (float)L0[pl*4+0][k] * wgt[pl*4+0])));
                const float t1 =
                    fmaf((float)L1[pl*4+3][k], wgt[pl*4+3],
                    fmaf((float)L1[pl*4+2][k], wgt[pl*4+2],
                    fmaf((float)L1[pl*4+1][k], wgt[pl*4+1],
                         (float)L1[pl*4+0][k] * wgt[pl*4+0])));
                if (pl == 0) { prod[k] = t0;  prod[8 + k] = t1; }
                else         { prod[k] *= t0; prod[8 + k] *= t1; }
            }
        }

        half8 o0, o1;
        #pragma unroll
        for (int k = 0; k < 8; ++k) {
            o0[k] = (_Float16)(prod[k]     * 256.0f);
            o1[k] = (_Float16)(prod[8 + k] * 256.0f);
        }
        *(half8*)&wbase[p * FEAT_STRIDE + hf * 16 + 0] = o0;
        *(half8*)&wbase[p * FEAT_STRIDE + hf * 16 + 8] = o1;
    }

    // a0 reads: same wave wrote these rows; lgkmcnt orders write->read.
    half8 a0[2];
    #pragma unroll
    for (int mt = 0; mt < 2; ++mt)
        a0[mt] = *(const half8*)&wbase[(mt * 16 + l15) * FEAT_STRIDE + quad * 8];

    // per-lane bias/weight scalars
    float b0v[8], b1v[8], w2s[8];
    #pragma unroll
    for (int nt = 0; nt < 8; ++nt) {
        b0v[nt] = b0[nt * 16 + l15] * 4096.0f;
        b1v[nt] = b1[nt * 16 + l15] * 4096.0f;
        w2s[nt] = w2[nt * 16 + l15] * (1.0f / 4096.0f);
    }

    // ================= layer 0 (h0 writes clobber feat region; WAR ordered
    // by lgkmcnt since a0 loads precede in program order) ===================
    #pragma unroll 1
    for (int nt = 0; nt < 8; ++nt) {
        const half8 bfr = *(const half8*)&w0h[(nt * 16 + l15) * NCH + quad * 8];
        f32x4 acc[2];
        #pragma unroll
        for (int mt = 0; mt < 2; ++mt) {
            acc[mt] = (f32x4){0.f, 0.f, 0.f, 0.f};
            acc[mt] = __builtin_amdgcn_mfma_f32_16x16x32_f16(
                a0[mt], bfr, acc[mt], 0, 0, 0);
        }
        #pragma unroll
        for (int mt = 0; mt < 2; ++mt)
            #pragma unroll
            for (int r = 0; r < 4; ++r) {
                const float hval = fmaxf(acc[mt][r] + b0v[nt], 0.0f);
                wbase[(mt * 16 + quad * 4 + r) * H0_STRIDE + nt * 16 + l15]
                    = (_Float16)hval;
            }
    }

    // ================= layer 1 (+ fused layer-2 epilogue) ==================
    half8 a1[2][4];
    #pragma unroll
    for (int mt = 0; mt < 2; ++mt)
        #pragma unroll
        for (int ks = 0; ks < 4; ++ks)
            a1[mt][ks] = *(const half8*)
                &wbase[(mt * 16 + l15) * H0_STRIDE + ks * 32 + quad * 8];

    float part[2][4];
    #pragma unroll
    for (int mt = 0; mt < 2; ++mt)
        #pragma unroll
        for (int r = 0; r < 4; ++r) part[mt][r] = 0.0f;

    #pragma unroll 2
    for (int nt = 0; nt < 8; ++nt) {
        f32x4 acc[2];
        #pragma unroll
        for (int mt = 0; mt < 2; ++mt) acc[mt] = (f32x4){0.f, 0.f, 0.f, 0.f};
        #pragma unroll
        for (int ks = 0; ks < 4; ++ks) {
            const half8 bfr = *(const half8*)
                &w1h[(nt * 16 + l15) * 128 + ks * 32 + quad * 8];
            #pragma unroll
            for (int mt = 0; mt < 2; ++mt)
                acc[mt] = __builtin_amdgcn_mfma_f32_16x16x32_f16(
                    a1[mt][ks], bfr, acc[mt], 0, 0, 0);
        }
        #pragma unroll
        for (int mt = 0; mt < 2; ++mt)
            #pragma unroll
            for (int r = 0; r < 4; ++r)
                part[mt][r] = fmaf(w2s[nt], fmaxf(acc[mt][r] + b1v[nt], 0.0f),
                                   part[mt][r]);
    }

    // reduce across the 16 lanes (l15) of each quad-group
    #pragma unroll
    for (int mt = 0; mt < 2; ++mt)
        #pragma unroll
        for (int r = 0; r < 4; ++r) {
            float s = part[mt][r];
            s += __shfl_xor(s, 1);
            s += __shfl_xor(s, 2);
            s += __shfl_xor(s, 4);
            s += __shfl_xor(s, 8);
            part[mt][r] = s;
        }

    if (l15 == 0) {
        const float bias2 = b2[0];
        const int base = blockIdx.x * 32;
        #pragma unroll
        for (int mt = 0; mt < 2; ++mt)
            #pragma unroll
            for (int r = 0; r < 4; ++r)
                out[base + mt * 16 + quad * 4 + r] = part[mt][r] + bias2;
    }
}

// ---------------------------------------------------------------------------
// Fallback (ws too small): round-1 fused fp32 kernel on original layout.
// ---------------------------------------------------------------------------
__global__ __launch_bounds__(256) void fused_fallback(
    const float* __restrict__ planes, const float* __restrict__ coords,
    const float* __restrict__ w0, const float* __restrict__ b0,
    const float* __restrict__ w1, const float* __restrict__ b1,
    const float* __restrict__ w2, const float* __restrict__ b2,
    float* __restrict__ out)
{
    const int t = blockIdx.x * 256 + threadIdx.x;
    const int b = t >> 17;
    const float cx = coords[(size_t)t * 3 + 0];
    const float cy = coords[(size_t)t * 3 + 1];
    const float cz = coords[(size_t)t * 3 + 2];
    float feat[NCH];
    #pragma unroll
    for (int p = 0; p < 3; ++p) {
        const float u = (p == 0) ? cx : (p == 1) ? cy : cx;
        const float v = (p == 0) ? cy : cz;
        const float fx = (u + 1.0f) * 0.5f * (RES - 1);
        const float fy = (v + 1.0f) * 0.5f * (RES - 1);
        const float x0f = floorf(fx), y0f = floorf(fy);
        const float wx = fx - x0f, wy = fy - y0f;
        const int x0 = (int)x0f, y0 = (int)y0f;
        const bool vx1 = (x0 + 1) < RES, vy1 = (y0 + 1) < RES;
        const int x1 = vx1 ? x0 + 1 : RES - 1;
        const int y1 = vy1 ? y0 + 1 : RES - 1;
        float w00 = (1.0f - wx) * (1.0f - wy), w01 = wx * (1.0f - wy);
        float w10 = (1.0f - wx) * wy, w11 = wx * wy;
        if (!vx1) { w01 = 0.0f; w11 = 0.0f; }
        if (!vy1) { w10 = 0.0f; w11 = 0.0f; }
        const float* base = planes + (size_t)(b * 3 + p) * NCH * RES * RES;
        const float* p00 = base + (size_t)y0 * RES + x0;
        const float* p01 = base + (size_t)y0 * RES + x1;
        const float* p10 = base + (size_t)y1 * RES + x0;
        const float* p11 = base + (size_t)y1 * RES + x1;
        #pragma unroll
        for (int c = 0; c < NCH; ++c) {
            const size_t off = (size_t)c * RES * RES;
            float s = p00[off] * w00;
            s = fmaf(p01[off], w01, s);
            s = fmaf(p10[off], w10, s);
            s = fmaf(p11[off], w11, s);
            if (p == 0) feat[c] = s; else feat[c] *= s;
        }
    }
    float h0[128];
    #pragma unroll
    for (int g = 0; g < 128; ++g) {
        const float* wr = w0 + g * NCH;
        float aA = b0[g], aB = 0.0f;
        #pragma unroll
        for (int c = 0; c < NCH; c += 2) {
            aA = fmaf(wr[c], feat[c], aA);
            aB = fmaf(wr[c + 1], feat[c + 1], aB);
        }
        h0[g] = fmaxf(aA + aB, 0.0f);
    }
    float o = b2[0];
    for (int g = 0; g < 128; ++g) {
        const float* wr = w1 + g * 128;
        float aA = b1[g], aB = 0.0f, aC = 0.0f, aD = 0.0f;
        #pragma unroll
        for (int h = 0; h < 128; h += 4) {
            aA = fmaf(wr[h], h0[h], aA);
            aB = fmaf(wr[h + 1], h0[h + 1], aB);
            aC = fmaf(wr[h + 2], h0[h + 2], aC);
            aD = fmaf(wr[h + 3], h0[h + 3], aD);
        }
        o = fmaf(fmaxf((aA + aB) + (aC + aD), 0.0f), w2[g], o);
    }
    out[t] = o;
}

// ---------------------------------------------------------------------------
extern "C" void kernel_launch(void* const* d_in, const int* in_sizes, int n_in,
                              void* d_out, int out_size, void* d_ws, size_t ws_size,
                              hipStream_t stream)
{
    const float* trip   = (const float*)d_in[0];
    const float* coords = (const float*)d_in[1];
    const float* w0     = (const float*)d_in[2];
    const float* b0     = (const float*)d_in[3];
    const float* w1     = (const float*)d_in[4];
    const float* b1     = (const float*)d_in[5];
    const float* w2     = (const float*)d_in[6];
    const float* b2     = (const float*)d_in[7];
    float* out = (float*)d_out;

    const size_t planesTBytes = (size_t)NB * 3 * RES * RES * NCH * 2;   // 50331648
    const size_t w0hBytes = 128 * NCH * 2;                              // 8192
    const size_t w1hBytes = 128 * 128 * 2;                              // 32768
    const size_t needed = planesTBytes + w0hBytes + w1hBytes;

    if (ws_size >= needed) {
        _Float16* planesT = (_Float16*)d_ws;
        _Float16* w0h     = (_Float16*)((char*)d_ws + planesTBytes);
        _Float16* w1h     = (_Float16*)((char*)d_ws + planesTBytes + w0hBytes);

        transpose_prep_kernel<<<dim3(RES, NB * 3 + 1), 256, 0, stream>>>(
            trip, w0, w1, planesT, w0h, w1h);
        fused_kernel<<<(NB * NPT) / 32, 64, 0, stream>>>(
            planesT, coords, w0h, w1h, b0, b1, w2, b2, out);
    } else {
        fused_fallback<<<(NB * NPT) / 256, 256, 0, stream>>>(
            trip, coords, w0, b0, w1, b1, w2, b2, out);
    }
}